// Round 8
// baseline (225.709 us; speedup 1.0000x reference)
//
#include <hip/hip_runtime.h>
#include <math.h>

// Shapes fixed by setup_inputs(): bs=2, m=16, v=16, L=40320, P=32, beta=1
#define BS 2
#define M 16
#define V 16
#define NROWB 136           // per-batch rows: 16 target + 120 i<j pairs
#define NROWS 272           // BS * NROWB
#define PMASK 32
#define KZ 32               // K-split blocks in k2 (grid.y)
#define KSTEPS 1260         // L / 32
#define NWORK 128           // KZ * 4 waves
#define TPB 5               // l-tiles (32 wide) per k1 block; 1260/5=252

typedef __attribute__((ext_vector_type(8))) short bf16x8;
typedef __attribute__((ext_vector_type(4))) float f32x4;

static __device__ __forceinline__ unsigned short f2bf(float x) {
    unsigned int u = __float_as_uint(x);
    unsigned int r = (u + 0x7FFFu + ((u >> 16) & 1u)) >> 16;
    return (unsigned short)r;
}

// -------- Kernel 1: double-buffered LDS-staged pair sums ------------------
// Block = (b, 5 tiles of 32 l). Tile = preds[b, :, :, l0:l0+32] = 256 rows
// x 128 B = 32 KB, staged via global_load_lds w=16 (1 KB/instr, 8 rows).
// Thread t: group g=t>>5 owns 17 rows, l-lane li=t&31.
// Pipeline per iter: [scalar loads] -> barrier (drains cur DMA) ->
//   issue next-tile DMA -> compute cur (DMA in flight).

static __device__ __forceinline__ void k1_stage(
    const float* __restrict__ preds, float* __restrict__ dst,
    int b, int l0t, int L, int lane, int wave)
{
#pragma unroll
    for (int n = 0; n < 8; ++n) {
        int chunk = wave * 8 + n;            // 0..31, 8 rows each
        int r0 = chunk * 8;
        const float* g = preds + (size_t)(b * 256 + r0 + (lane >> 3)) * L
                         + l0t + (lane & 7) * 4;
        __builtin_amdgcn_global_load_lds(
            (const __attribute__((address_space(1))) unsigned int*)g,
            (__attribute__((address_space(3))) unsigned int*)(dst + chunk * 256),
            16, 0, 0);
    }
}

template<int G>
static __device__ __forceinline__ void k1_compute(
    const float* __restrict__ xsb,           // current 32-KB tile
    const float* __restrict__ tg,            // 16 target values (G==0 lanes)
    const float* __restrict__ scale, float wl,
    int b, int li, int l, int L,
    unsigned short* __restrict__ S)
{
    float acc[17];
#pragma unroll
    for (int r = 0; r < 17; ++r) acc[r] = 0.0f;

    const int base = (G == 0) ? 0 : 17 * G - 16;   // first pair idx
    const int npair = (G == 0) ? 1 : 17;
    const int aoff = (G == 0) ? 16 : 0;

    for (int v = 0; v < V; ++v) {
        float sw = scale[v] * wl;
        float x[M];
#pragma unroll
        for (int i = 0; i < M; ++i)
            x[i] = xsb[(i * 16 + v) * 32 + li] * sw;
        if (G == 0) {
            float y = tg[v] * sw;
#pragma unroll
            for (int i = 0; i < M; ++i) {
                float d = x[i] - y;
                acc[i] = fmaf(d, d, acc[i]);
            }
        }
        int k = 0;
#pragma unroll
        for (int i = 0; i < M; ++i) {
#pragma unroll
            for (int j = i + 1; j < M; ++j) {
                if (k >= base && k < base + npair) {
                    float d = x[i] - x[j];
                    acc[aoff + k - base] = fmaf(d, d, acc[aoff + k - base]);
                }
                ++k;
            }
        }
    }
#pragma unroll
    for (int r = 0; r < 17; ++r)
        S[(size_t)(b * NROWB + 17 * G + r) * L + l] = f2bf(acc[r]);
}

__global__ __launch_bounds__(256, 2)
void k1_pairsums(const float* __restrict__ preds, const float* __restrict__ target,
                 const float* __restrict__ weights, const float* __restrict__ scale,
                 const float* __restrict__ masks,
                 unsigned short* __restrict__ S, unsigned short* __restrict__ maskbf,
                 int L)
{
    __shared__ float xs[2][8192];            // 2 x 32 KB
    int t = (int)threadIdx.x;
    int lane = t & 63, wave = t >> 6;
    int g = t >> 5, li = t & 31;
    int tile0 = (int)blockIdx.x * TPB;       // tile idx in batch, 0..1259
    int b = (int)blockIdx.y;

    // prologue: DMA tile 0 into buf 0
    k1_stage(preds, &xs[0][0], b, tile0 * 32, L, lane, wave);

    for (int it = 0; it < TPB; ++it) {
        int l0t = (tile0 + it) * 32;
        int l = l0t + li;

        // scalar global loads for THIS tile, issued before the barrier so
        // their waits don't force the next-tile DMA to drain.
        float wl = weights[l];
        float tg[V];
        if (g == 0) {
#pragma unroll
            for (int v = 0; v < V; ++v)
                tg[v] = target[(size_t)(b * V + v) * L + l];
        }
        unsigned short mk[4];
        if (b == 0) {
#pragma unroll
            for (int pp = 0; pp < 4; ++pp) {
                int p = g * 4 + pp;
                mk[pp] = (masks[(size_t)p * L + l] != 0.0f) ? (unsigned short)0x3F80
                                                            : (unsigned short)0;
            }
        }

        __syncthreads();                     // DMA(it) + scalar loads complete

        if (it + 1 < TPB)                    // DMA(it+1) in flight during compute
            k1_stage(preds, &xs[(it + 1) & 1][0], b, (tile0 + it + 1) * 32, L,
                     lane, wave);

        if (b == 0) {
#pragma unroll
            for (int pp = 0; pp < 4; ++pp)
                maskbf[(size_t)(g * 4 + pp) * L + l] = mk[pp];
        }

        const float* xsb = &xs[it & 1][0];
        switch (g) {
            case 0: k1_compute<0>(xsb, tg, scale, wl, b, li, l, L, S); break;
            case 1: k1_compute<1>(xsb, tg, scale, wl, b, li, l, L, S); break;
            case 2: k1_compute<2>(xsb, tg, scale, wl, b, li, l, L, S); break;
            case 3: k1_compute<3>(xsb, tg, scale, wl, b, li, l, L, S); break;
            case 4: k1_compute<4>(xsb, tg, scale, wl, b, li, l, L, S); break;
            case 5: k1_compute<5>(xsb, tg, scale, wl, b, li, l, L, S); break;
            case 6: k1_compute<6>(xsb, tg, scale, wl, b, li, l, L, S); break;
            default: k1_compute<7>(xsb, tg, scale, wl, b, li, l, L, S); break;
        }
    }
}

// -------- Kernel 2: MFMA GEMM  D2[row][p] = sum_l S[row][l] * maskbf[p][l]
__global__ __launch_bounds__(256, 4)
void k2_mfma(const unsigned short* __restrict__ S,
             const unsigned short* __restrict__ maskbf,
             float* __restrict__ D2p, float* __restrict__ out, int L)
{
    if (blockIdx.x == 0 && blockIdx.y == 0 && threadIdx.x == 0)
        out[0] = 0.0f;                       // k3 atomics are stream-ordered after k2

    int lane = (int)(threadIdx.x & 63);
    int wave = (int)(threadIdx.x >> 6);
    int mtile = blockIdx.x;            // 0..16
    int z = blockIdx.y;                // 0..KZ-1
    int zw = z * 4 + wave;             // 0..127 K-workers

    const int q = KSTEPS / NWORK;      // 9
    const int rem = KSTEPS % NWORK;    // 108
    int start = zw * q + (zw < rem ? zw : rem);
    int cnt = q + (zw < rem ? 1 : 0);

    const unsigned short* Arow =
        S + (size_t)(mtile * 16 + (lane & 15)) * L + (lane >> 4) * 8;
    const unsigned short* B0 =
        maskbf + (size_t)(lane & 15) * L + (lane >> 4) * 8;
    const unsigned short* B1 =
        maskbf + (size_t)(16 + (lane & 15)) * L + (lane >> 4) * 8;

    f32x4 acc0 = {0.f, 0.f, 0.f, 0.f};
    f32x4 acc1 = {0.f, 0.f, 0.f, 0.f};

    for (int s = 0; s < cnt; ++s) {
        int k0 = (start + s) * 32;
        bf16x8 a  = *(const bf16x8*)(Arow + k0);
        bf16x8 b0 = *(const bf16x8*)(B0 + k0);
        bf16x8 b1 = *(const bf16x8*)(B1 + k0);
        acc0 = __builtin_amdgcn_mfma_f32_16x16x32_bf16(a, b0, acc0, 0, 0, 0);
        acc1 = __builtin_amdgcn_mfma_f32_16x16x32_bf16(a, b1, acc1, 0, 0, 0);
    }

    __shared__ float red[4][512];
    int c16 = lane & 15;
#pragma unroll
    for (int reg = 0; reg < 4; ++reg) {
        int r16 = (lane >> 4) * 4 + reg;
        red[wave][r16 * 16 + c16]       = acc0[reg];
        red[wave][256 + r16 * 16 + c16] = acc1[reg];
    }
    __syncthreads();
    int t = (int)threadIdx.x;
#pragma unroll
    for (int u = t; u < 512; u += 256) {
        float v = red[0][u] + red[1][u] + red[2][u] + red[3][u];
        D2p[((size_t)z * 17 + mtile) * 512 + u] = v;
    }
}

// -------- Kernel 3: parallel z-sum, sqrt, weighted reduce, atomic ---------
__global__ __launch_bounds__(256, 2)
void k3_finalize(const float* __restrict__ D2p, const int* __restrict__ beta_p,
                 float* __restrict__ out)
{
    int t = (int)threadIdx.x;
    int e = blockIdx.x * 256 + t;          // 0..8703, grid exact
    int mtile = e >> 9;
    int flat = e & 511;

    float vbuf[KZ];
#pragma unroll
    for (int z = 0; z < KZ; ++z)
        vbuf[z] = D2p[((size_t)z * 17 + mtile) * 512 + flat];

    float a0 = 0.f, a1 = 0.f, a2 = 0.f, a3 = 0.f;
#pragma unroll
    for (int z = 0; z < KZ; z += 4) {
        a0 += vbuf[z + 0]; a1 += vbuf[z + 1];
        a2 += vbuf[z + 2]; a3 += vbuf[z + 3];
    }
    float d2 = fmaxf((a0 + a1) + (a2 + a3), 0.0f);
    float beta = (float)beta_p[0];
    float d = (beta == 1.0f) ? sqrtf(d2) : powf(d2, 0.5f * beta);

    const float wa = 1.0f / (float)(BS * M);
    const float wb = -1.0f / (float)(BS * M * (M - 1));
    int row = mtile * 16 + ((flat >> 4) & 15);
    int local = row % NROWB;
    float sum = ((local < M) ? wa : wb) * d;

    int lane = t & 63, wv = t >> 6;
#pragma unroll
    for (int off = 32; off > 0; off >>= 1)
        sum += __shfl_down(sum, off, 64);
    __shared__ float red[4];
    if (lane == 0) red[wv] = sum;
    __syncthreads();
    if (t == 0)
        atomicAdd(out, red[0] + red[1] + red[2] + red[3]);
}

extern "C" void kernel_launch(void* const* d_in, const int* in_sizes, int n_in,
                              void* d_out, int out_size, void* d_ws, size_t ws_size,
                              hipStream_t stream)
{
    const float* preds   = (const float*)d_in[0];
    const float* target  = (const float*)d_in[1];
    const float* weights = (const float*)d_in[2];
    const float* scale   = (const float*)d_in[3];
    const float* masks   = (const float*)d_in[4];
    const int*   beta    = (const int*)d_in[5];
    float* out = (float*)d_out;

    int L = in_sizes[2];   // 40320 = 1260*32

    unsigned short* S = (unsigned short*)d_ws;                   // 272*L bf16
    size_t s_bytes = (size_t)NROWS * (size_t)L * sizeof(unsigned short);
    unsigned short* maskbf = (unsigned short*)((char*)d_ws + ((s_bytes + 255) & ~(size_t)255));
    size_t m_bytes = (size_t)PMASK * (size_t)L * sizeof(unsigned short);
    float* D2p = (float*)((char*)maskbf + ((m_bytes + 255) & ~(size_t)255)); // KZ*17*512 f32

    dim3 g1((L / 32) / TPB, BS);           // 252 x 2
    k1_pairsums<<<g1, 256, 0, stream>>>(preds, target, weights, scale, masks,
                                        S, maskbf, L);

    dim3 g2(17, KZ);
    k2_mfma<<<g2, 256, 0, stream>>>(S, maskbf, D2p, out, L);

    k3_finalize<<<(NROWS * PMASK) / 256, 256, 0, stream>>>(D2p, beta, out);
}

// Round 9
// 224.551 us; speedup vs baseline: 1.0052x; 1.0052x over previous
//
#include <hip/hip_runtime.h>
#include <math.h>

// Shapes fixed by setup_inputs(): bs=2, m=16, v=16, L=40320, P=32, beta=1
#define BS 2
#define M 16
#define V 16
#define NROWB 136           // per-batch rows: 16 target + 120 i<j pairs
#define NROWS 272           // BS * NROWB
#define PMASK 32
#define KZ 32               // K-split blocks in k2 (grid.y)
#define KSTEPS 1260         // L / 32
#define NWORK 128           // KZ * 4 waves

typedef __attribute__((ext_vector_type(8))) short bf16x8;
typedef __attribute__((ext_vector_type(4))) float f32x4;

static __device__ __forceinline__ unsigned short f2bf(float x) {
    unsigned int u = __float_as_uint(x);
    unsigned int r = (u + 0x7FFFu + ((u >> 16) & 1u)) >> 16;
    return (unsigned short)r;
}

// -------- Kernel 1: v-chunked LDS-staged pair sums ------------------------
// Block = (b, 64 l's). Chunk c = preds[b, :, 8c:8c+8, l0:l0+64] = 128 rows
// x 256 B = 32 KB staged via global_load_lds w=16. acc[34] persists across
// the 2 chunks. Wave W computes local rows [34W, 34W+34) (wave-uniform).
// 32 KB LDS -> 4-5 blocks/CU; cross-block overlap hides staging.

static __device__ __forceinline__ void k1_stage(
    const float* __restrict__ preds, float* __restrict__ dst,
    int b, int v0, int l0, int L, int lane, int wave)
{
    // 128 rows (i*8+vc); wave stages 32 rows = 8 instrs x 4 rows (1 KB each)
#pragma unroll
    for (int n = 0; n < 8; ++n) {
        int r0 = wave * 32 + n * 4;               // row group, r0%8 in {0,4}
        int grow = b * 256 + (r0 >> 3) * 16 + v0 + (r0 & 7);
        const float* g = preds + (size_t)(grow + (lane >> 4)) * L
                         + l0 + (lane & 15) * 4;
        __builtin_amdgcn_global_load_lds(
            (const __attribute__((address_space(1))) unsigned int*)g,
            (__attribute__((address_space(3))) unsigned int*)(dst + r0 * 64),
            16, 0, 0);
    }
}

template<int W>
static __device__ __forceinline__ void k1_chunk(
    const float (*__restrict__ xs)[64],           // [i*8+vc][l]
    const float* __restrict__ target,
    const float* __restrict__ scale, float wl,
    int b, int lane, int l0, int L, int v0,
    float* __restrict__ acc)
{
    const int base = (W == 0) ? 0 : 34 * W - 16;  // first pair idx
    const int npair = (W == 0) ? 18 : 34;
    const int aoff = (W == 0) ? 16 : 0;

#pragma unroll
    for (int vc = 0; vc < 8; ++vc) {
        int v = v0 + vc;
        float sw = scale[v] * wl;
        float x[M];
#pragma unroll
        for (int i = 0; i < M; ++i)
            x[i] = xs[i * 8 + vc][lane] * sw;
        if (W == 0) {
            float y = target[(size_t)(b * V + v) * L + l0 + lane] * sw;
#pragma unroll
            for (int i = 0; i < M; ++i) {
                float d = x[i] - y;
                acc[i] = fmaf(d, d, acc[i]);
            }
        }
        int k = 0;
#pragma unroll
        for (int i = 0; i < M; ++i) {
#pragma unroll
            for (int j = i + 1; j < M; ++j) {
                if (k >= base && k < base + npair) {
                    float d = x[i] - x[j];
                    acc[aoff + k - base] = fmaf(d, d, acc[aoff + k - base]);
                }
                ++k;
            }
        }
    }
}

__global__ __launch_bounds__(256, 4)
void k1_pairsums(const float* __restrict__ preds, const float* __restrict__ target,
                 const float* __restrict__ weights, const float* __restrict__ scale,
                 const float* __restrict__ masks,
                 unsigned short* __restrict__ S, unsigned short* __restrict__ maskbf,
                 int L)
{
    __shared__ float xs[128][64];                 // 32 KB
    int t = (int)threadIdx.x;
    int lane = t & 63, wave = t >> 6;
    int l0 = (int)blockIdx.x * 64;
    int b = (int)blockIdx.y;

    k1_stage(preds, &xs[0][0], b, 0, l0, L, lane, wave);

    // per-thread scalars + mask conversion (before first barrier)
    float wl = weights[l0 + lane];
    if (b == 0) {
#pragma unroll
        for (int pp = 0; pp < 8; ++pp) {
            int p = wave * 8 + pp;
            maskbf[(size_t)p * L + l0 + lane] =
                (masks[(size_t)p * L + l0 + lane] != 0.0f) ? (unsigned short)0x3F80
                                                           : (unsigned short)0;
        }
    }

    float acc[34];
#pragma unroll
    for (int r = 0; r < 34; ++r) acc[r] = 0.0f;

    __syncthreads();                              // chunk 0 staged

    switch (wave) {
        case 0: k1_chunk<0>(xs, target, scale, wl, b, lane, l0, L, 0, acc); break;
        case 1: k1_chunk<1>(xs, target, scale, wl, b, lane, l0, L, 0, acc); break;
        case 2: k1_chunk<2>(xs, target, scale, wl, b, lane, l0, L, 0, acc); break;
        default: k1_chunk<3>(xs, target, scale, wl, b, lane, l0, L, 0, acc); break;
    }

    __syncthreads();                              // all waves done reading chunk 0
    k1_stage(preds, &xs[0][0], b, 8, l0, L, lane, wave);
    __syncthreads();                              // chunk 1 staged

    switch (wave) {
        case 0: k1_chunk<0>(xs, target, scale, wl, b, lane, l0, L, 8, acc); break;
        case 1: k1_chunk<1>(xs, target, scale, wl, b, lane, l0, L, 8, acc); break;
        case 2: k1_chunk<2>(xs, target, scale, wl, b, lane, l0, L, 8, acc); break;
        default: k1_chunk<3>(xs, target, scale, wl, b, lane, l0, L, 8, acc); break;
    }

#pragma unroll
    for (int r = 0; r < 34; ++r)
        S[(size_t)(b * NROWB + 34 * wave + r) * L + l0 + lane] = f2bf(acc[r]);
}

// -------- Kernel 2: MFMA GEMM  D2[row][p] = sum_l S[row][l] * maskbf[p][l]
__global__ __launch_bounds__(256, 4)
void k2_mfma(const unsigned short* __restrict__ S,
             const unsigned short* __restrict__ maskbf,
             float* __restrict__ D2p, float* __restrict__ out, int L)
{
    if (blockIdx.x == 0 && blockIdx.y == 0 && threadIdx.x == 0)
        out[0] = 0.0f;                            // k3 atomics stream-ordered after k2

    int lane = (int)(threadIdx.x & 63);
    int wave = (int)(threadIdx.x >> 6);
    int mtile = blockIdx.x;            // 0..16
    int z = blockIdx.y;                // 0..KZ-1
    int zw = z * 4 + wave;             // 0..127 K-workers

    const int q = KSTEPS / NWORK;      // 9
    const int rem = KSTEPS % NWORK;    // 108
    int start = zw * q + (zw < rem ? zw : rem);
    int cnt = q + (zw < rem ? 1 : 0);

    const unsigned short* Arow =
        S + (size_t)(mtile * 16 + (lane & 15)) * L + (lane >> 4) * 8;
    const unsigned short* B0 =
        maskbf + (size_t)(lane & 15) * L + (lane >> 4) * 8;
    const unsigned short* B1 =
        maskbf + (size_t)(16 + (lane & 15)) * L + (lane >> 4) * 8;

    f32x4 acc0 = {0.f, 0.f, 0.f, 0.f};
    f32x4 acc1 = {0.f, 0.f, 0.f, 0.f};

    for (int s = 0; s < cnt; ++s) {
        int k0 = (start + s) * 32;
        bf16x8 a  = *(const bf16x8*)(Arow + k0);
        bf16x8 b0 = *(const bf16x8*)(B0 + k0);
        bf16x8 b1 = *(const bf16x8*)(B1 + k0);
        acc0 = __builtin_amdgcn_mfma_f32_16x16x32_bf16(a, b0, acc0, 0, 0, 0);
        acc1 = __builtin_amdgcn_mfma_f32_16x16x32_bf16(a, b1, acc1, 0, 0, 0);
    }

    __shared__ float red[4][512];
    int c16 = lane & 15;
#pragma unroll
    for (int reg = 0; reg < 4; ++reg) {
        int r16 = (lane >> 4) * 4 + reg;
        red[wave][r16 * 16 + c16]       = acc0[reg];
        red[wave][256 + r16 * 16 + c16] = acc1[reg];
    }
    __syncthreads();
    int t = (int)threadIdx.x;
#pragma unroll
    for (int u = t; u < 512; u += 256) {
        float v = red[0][u] + red[1][u] + red[2][u] + red[3][u];
        D2p[((size_t)z * 17 + mtile) * 512 + u] = v;
    }
}

// -------- Kernel 3: parallel z-sum, sqrt, weighted reduce, atomic ---------
__global__ __launch_bounds__(256, 2)
void k3_finalize(const float* __restrict__ D2p, const int* __restrict__ beta_p,
                 float* __restrict__ out)
{
    int t = (int)threadIdx.x;
    int e = blockIdx.x * 256 + t;          // 0..8703, grid exact
    int mtile = e >> 9;
    int flat = e & 511;

    float vbuf[KZ];
#pragma unroll
    for (int z = 0; z < KZ; ++z)
        vbuf[z] = D2p[((size_t)z * 17 + mtile) * 512 + flat];

    float a0 = 0.f, a1 = 0.f, a2 = 0.f, a3 = 0.f;
#pragma unroll
    for (int z = 0; z < KZ; z += 4) {
        a0 += vbuf[z + 0]; a1 += vbuf[z + 1];
        a2 += vbuf[z + 2]; a3 += vbuf[z + 3];
    }
    float d2 = fmaxf((a0 + a1) + (a2 + a3), 0.0f);
    float beta = (float)beta_p[0];
    float d = (beta == 1.0f) ? sqrtf(d2) : powf(d2, 0.5f * beta);

    const float wa = 1.0f / (float)(BS * M);
    const float wb = -1.0f / (float)(BS * M * (M - 1));
    int row = mtile * 16 + ((flat >> 4) & 15);
    int local = row % NROWB;
    float sum = ((local < M) ? wa : wb) * d;

    int lane = t & 63, wv = t >> 6;
#pragma unroll
    for (int off = 32; off > 0; off >>= 1)
        sum += __shfl_down(sum, off, 64);
    __shared__ float red[4];
    if (lane == 0) red[wv] = sum;
    __syncthreads();
    if (t == 0)
        atomicAdd(out, red[0] + red[1] + red[2] + red[3]);
}

extern "C" void kernel_launch(void* const* d_in, const int* in_sizes, int n_in,
                              void* d_out, int out_size, void* d_ws, size_t ws_size,
                              hipStream_t stream)
{
    const float* preds   = (const float*)d_in[0];
    const float* target  = (const float*)d_in[1];
    const float* weights = (const float*)d_in[2];
    const float* scale   = (const float*)d_in[3];
    const float* masks   = (const float*)d_in[4];
    const int*   beta    = (const int*)d_in[5];
    float* out = (float*)d_out;

    int L = in_sizes[2];   // 40320 = 630*64 = 1260*32

    unsigned short* S = (unsigned short*)d_ws;                   // 272*L bf16
    size_t s_bytes = (size_t)NROWS * (size_t)L * sizeof(unsigned short);
    unsigned short* maskbf = (unsigned short*)((char*)d_ws + ((s_bytes + 255) & ~(size_t)255));
    size_t m_bytes = (size_t)PMASK * (size_t)L * sizeof(unsigned short);
    float* D2p = (float*)((char*)maskbf + ((m_bytes + 255) & ~(size_t)255)); // KZ*17*512 f32

    dim3 g1(L / 64, BS);                   // 630 x 2
    k1_pairsums<<<g1, 256, 0, stream>>>(preds, target, weights, scale, masks,
                                        S, maskbf, L);

    dim3 g2(17, KZ);
    k2_mfma<<<g2, 256, 0, stream>>>(S, maskbf, D2p, out, L);

    k3_finalize<<<(NROWS * PMASK) / 256, 256, 0, stream>>>(D2p, beta, out);
}

// Round 10
// 159.039 us; speedup vs baseline: 1.4192x; 1.4119x over previous
//
#include <hip/hip_runtime.h>
#include <math.h>

// Shapes fixed by setup_inputs(): bs=2, m=16, v=16, L=40320, P=32, beta=1
#define BS 2
#define M 16
#define V 16
#define NROWB 136           // per-batch rows: 16 target + 120 i<j pairs
#define NROWS 272           // BS * NROWB
#define PMASK 32
#define KZ 32               // K-split blocks in k2 (grid.y)
#define KSTEPS 1260         // L / 32
#define NWORK 128           // KZ * 4 waves

typedef __attribute__((ext_vector_type(8))) short bf16x8;
typedef __attribute__((ext_vector_type(4))) float f32x4;

static __device__ __forceinline__ unsigned short f2bf(float x) {
    unsigned int u = __float_as_uint(x);
    unsigned int r = (u + 0x7FFFu + ((u >> 16) & 1u)) >> 16;
    return (unsigned short)r;
}

// -------- Kernel 1: v-chunked LDS-staged pair sums ------------------------
// Block = (b, 64 l's). Chunk c = preds[b, :, 8c:8c+8, l0:l0+64] = 128 rows
// x 256 B = 32 KB staged via global_load_lds w=16. acc[34] persists across
// the 2 chunks. Wave W computes local rows [34W, 34W+34) (wave-uniform).
// NOTE: __launch_bounds__ min_waves MUST stay 2 — at 4 the allocator chases
// the 64-reg tier and spills acc[] to scratch (R8: +100 MB WRITE, 110 us).

static __device__ __forceinline__ void k1_stage(
    const float* __restrict__ preds, float* __restrict__ dst,
    int b, int v0, int l0, int L, int lane, int wave)
{
    // 128 rows (i*8+vc); wave stages 32 rows = 8 instrs x 4 rows (1 KB each)
#pragma unroll
    for (int n = 0; n < 8; ++n) {
        int r0 = wave * 32 + n * 4;               // row group, r0%8 in {0,4}
        int grow = b * 256 + (r0 >> 3) * 16 + v0 + (r0 & 7);
        const float* g = preds + (size_t)(grow + (lane >> 4)) * L
                         + l0 + (lane & 15) * 4;
        __builtin_amdgcn_global_load_lds(
            (const __attribute__((address_space(1))) unsigned int*)g,
            (__attribute__((address_space(3))) unsigned int*)(dst + r0 * 64),
            16, 0, 0);
    }
}

template<int W>
static __device__ __forceinline__ void k1_chunk(
    const float (*__restrict__ xs)[64],           // [i*8+vc][l]
    const float* __restrict__ target,
    const float* __restrict__ scale, float wl,
    int b, int lane, int l0, int L, int v0,
    float* __restrict__ acc)
{
    const int base = (W == 0) ? 0 : 34 * W - 16;  // first pair idx
    const int npair = (W == 0) ? 18 : 34;
    const int aoff = (W == 0) ? 16 : 0;

#pragma unroll
    for (int vc = 0; vc < 8; ++vc) {
        int v = v0 + vc;
        float sw = scale[v] * wl;
        float x[M];
#pragma unroll
        for (int i = 0; i < M; ++i)
            x[i] = xs[i * 8 + vc][lane] * sw;
        if (W == 0) {
            float y = target[(size_t)(b * V + v) * L + l0 + lane] * sw;
#pragma unroll
            for (int i = 0; i < M; ++i) {
                float d = x[i] - y;
                acc[i] = fmaf(d, d, acc[i]);
            }
        }
        int k = 0;
#pragma unroll
        for (int i = 0; i < M; ++i) {
#pragma unroll
            for (int j = i + 1; j < M; ++j) {
                if (k >= base && k < base + npair) {
                    float d = x[i] - x[j];
                    acc[aoff + k - base] = fmaf(d, d, acc[aoff + k - base]);
                }
                ++k;
            }
        }
    }
}

__global__ __launch_bounds__(256, 2)
void k1_pairsums(const float* __restrict__ preds, const float* __restrict__ target,
                 const float* __restrict__ weights, const float* __restrict__ scale,
                 const float* __restrict__ masks,
                 unsigned short* __restrict__ S, unsigned short* __restrict__ maskbf,
                 int L)
{
    __shared__ float xs[128][64];                 // 32 KB
    int t = (int)threadIdx.x;
    int lane = t & 63, wave = t >> 6;
    int l0 = (int)blockIdx.x * 64;
    int b = (int)blockIdx.y;

    k1_stage(preds, &xs[0][0], b, 0, l0, L, lane, wave);

    // per-thread scalars + mask conversion (before first barrier)
    float wl = weights[l0 + lane];
    if (b == 0) {
#pragma unroll
        for (int pp = 0; pp < 8; ++pp) {
            int p = wave * 8 + pp;
            maskbf[(size_t)p * L + l0 + lane] =
                (masks[(size_t)p * L + l0 + lane] != 0.0f) ? (unsigned short)0x3F80
                                                           : (unsigned short)0;
        }
    }

    float acc[34];
#pragma unroll
    for (int r = 0; r < 34; ++r) acc[r] = 0.0f;

    __syncthreads();                              // chunk 0 staged

    switch (wave) {
        case 0: k1_chunk<0>(xs, target, scale, wl, b, lane, l0, L, 0, acc); break;
        case 1: k1_chunk<1>(xs, target, scale, wl, b, lane, l0, L, 0, acc); break;
        case 2: k1_chunk<2>(xs, target, scale, wl, b, lane, l0, L, 0, acc); break;
        default: k1_chunk<3>(xs, target, scale, wl, b, lane, l0, L, 0, acc); break;
    }

    __syncthreads();                              // all waves done reading chunk 0
    k1_stage(preds, &xs[0][0], b, 8, l0, L, lane, wave);
    __syncthreads();                              // chunk 1 staged

    switch (wave) {
        case 0: k1_chunk<0>(xs, target, scale, wl, b, lane, l0, L, 8, acc); break;
        case 1: k1_chunk<1>(xs, target, scale, wl, b, lane, l0, L, 8, acc); break;
        case 2: k1_chunk<2>(xs, target, scale, wl, b, lane, l0, L, 8, acc); break;
        default: k1_chunk<3>(xs, target, scale, wl, b, lane, l0, L, 8, acc); break;
    }

#pragma unroll
    for (int r = 0; r < 34; ++r)
        S[(size_t)(b * NROWB + 34 * wave + r) * L + l0 + lane] = f2bf(acc[r]);
}

// -------- Kernel 2: MFMA GEMM  D2[row][p] = sum_l S[row][l] * maskbf[p][l]
__global__ __launch_bounds__(256, 4)
void k2_mfma(const unsigned short* __restrict__ S,
             const unsigned short* __restrict__ maskbf,
             float* __restrict__ D2p, float* __restrict__ out, int L)
{
    if (blockIdx.x == 0 && blockIdx.y == 0 && threadIdx.x == 0)
        out[0] = 0.0f;                            // k3 atomics stream-ordered after k2

    int lane = (int)(threadIdx.x & 63);
    int wave = (int)(threadIdx.x >> 6);
    int mtile = blockIdx.x;            // 0..16
    int z = blockIdx.y;                // 0..KZ-1
    int zw = z * 4 + wave;             // 0..127 K-workers

    const int q = KSTEPS / NWORK;      // 9
    const int rem = KSTEPS % NWORK;    // 108
    int start = zw * q + (zw < rem ? zw : rem);
    int cnt = q + (zw < rem ? 1 : 0);

    const unsigned short* Arow =
        S + (size_t)(mtile * 16 + (lane & 15)) * L + (lane >> 4) * 8;
    const unsigned short* B0 =
        maskbf + (size_t)(lane & 15) * L + (lane >> 4) * 8;
    const unsigned short* B1 =
        maskbf + (size_t)(16 + (lane & 15)) * L + (lane >> 4) * 8;

    f32x4 acc0 = {0.f, 0.f, 0.f, 0.f};
    f32x4 acc1 = {0.f, 0.f, 0.f, 0.f};

    for (int s = 0; s < cnt; ++s) {
        int k0 = (start + s) * 32;
        bf16x8 a  = *(const bf16x8*)(Arow + k0);
        bf16x8 b0 = *(const bf16x8*)(B0 + k0);
        bf16x8 b1 = *(const bf16x8*)(B1 + k0);
        acc0 = __builtin_amdgcn_mfma_f32_16x16x32_bf16(a, b0, acc0, 0, 0, 0);
        acc1 = __builtin_amdgcn_mfma_f32_16x16x32_bf16(a, b1, acc1, 0, 0, 0);
    }

    __shared__ float red[4][512];
    int c16 = lane & 15;
#pragma unroll
    for (int reg = 0; reg < 4; ++reg) {
        int r16 = (lane >> 4) * 4 + reg;
        red[wave][r16 * 16 + c16]       = acc0[reg];
        red[wave][256 + r16 * 16 + c16] = acc1[reg];
    }
    __syncthreads();
    int t = (int)threadIdx.x;
#pragma unroll
    for (int u = t; u < 512; u += 256) {
        float v = red[0][u] + red[1][u] + red[2][u] + red[3][u];
        D2p[((size_t)z * 17 + mtile) * 512 + u] = v;
    }
}

// -------- Kernel 3: parallel z-sum, sqrt, weighted reduce, atomic ---------
__global__ __launch_bounds__(256, 2)
void k3_finalize(const float* __restrict__ D2p, const int* __restrict__ beta_p,
                 float* __restrict__ out)
{
    int t = (int)threadIdx.x;
    int e = blockIdx.x * 256 + t;          // 0..8703, grid exact
    int mtile = e >> 9;
    int flat = e & 511;

    float vbuf[KZ];
#pragma unroll
    for (int z = 0; z < KZ; ++z)
        vbuf[z] = D2p[((size_t)z * 17 + mtile) * 512 + flat];

    float a0 = 0.f, a1 = 0.f, a2 = 0.f, a3 = 0.f;
#pragma unroll
    for (int z = 0; z < KZ; z += 4) {
        a0 += vbuf[z + 0]; a1 += vbuf[z + 1];
        a2 += vbuf[z + 2]; a3 += vbuf[z + 3];
    }
    float d2 = fmaxf((a0 + a1) + (a2 + a3), 0.0f);
    float beta = (float)beta_p[0];
    float d = (beta == 1.0f) ? sqrtf(d2) : powf(d2, 0.5f * beta);

    const float wa = 1.0f / (float)(BS * M);
    const float wb = -1.0f / (float)(BS * M * (M - 1));
    int row = mtile * 16 + ((flat >> 4) & 15);
    int local = row % NROWB;
    float sum = ((local < M) ? wa : wb) * d;

    int lane = t & 63, wv = t >> 6;
#pragma unroll
    for (int off = 32; off > 0; off >>= 1)
        sum += __shfl_down(sum, off, 64);
    __shared__ float red[4];
    if (lane == 0) red[wv] = sum;
    __syncthreads();
    if (t == 0)
        atomicAdd(out, red[0] + red[1] + red[2] + red[3]);
}

extern "C" void kernel_launch(void* const* d_in, const int* in_sizes, int n_in,
                              void* d_out, int out_size, void* d_ws, size_t ws_size,
                              hipStream_t stream)
{
    const float* preds   = (const float*)d_in[0];
    const float* target  = (const float*)d_in[1];
    const float* weights = (const float*)d_in[2];
    const float* scale   = (const float*)d_in[3];
    const float* masks   = (const float*)d_in[4];
    const int*   beta    = (const int*)d_in[5];
    float* out = (float*)d_out;

    int L = in_sizes[2];   // 40320 = 630*64 = 1260*32

    unsigned short* S = (unsigned short*)d_ws;                   // 272*L bf16
    size_t s_bytes = (size_t)NROWS * (size_t)L * sizeof(unsigned short);
    unsigned short* maskbf = (unsigned short*)((char*)d_ws + ((s_bytes + 255) & ~(size_t)255));
    size_t m_bytes = (size_t)PMASK * (size_t)L * sizeof(unsigned short);
    float* D2p = (float*)((char*)maskbf + ((m_bytes + 255) & ~(size_t)255)); // KZ*17*512 f32

    dim3 g1(L / 64, BS);                   // 630 x 2
    k1_pairsums<<<g1, 256, 0, stream>>>(preds, target, weights, scale, masks,
                                        S, maskbf, L);

    dim3 g2(17, KZ);
    k2_mfma<<<g2, 256, 0, stream>>>(S, maskbf, D2p, out, L);

    k3_finalize<<<(NROWS * PMASK) / 256, 256, 0, stream>>>(D2p, beta, out);
}

// Round 11
// 155.515 us; speedup vs baseline: 1.4514x; 1.0227x over previous
//
#include <hip/hip_runtime.h>
#include <math.h>

// Shapes fixed by setup_inputs(): bs=2, m=16, v=16, L=40320, P=32, beta=1
#define BS 2
#define M 16
#define V 16
#define NROWB 136           // per-batch rows: 16 target + 120 i<j pairs
#define NROWS 272           // BS * NROWB
#define PMASK 32
#define KZ 32               // K-split blocks in k2 (grid.y)
#define KSTEPS 1260         // L / 32
#define NWORK 128           // KZ * 4 waves

typedef __attribute__((ext_vector_type(8))) short bf16x8;
typedef __attribute__((ext_vector_type(4))) float f32x4;

static __device__ __forceinline__ unsigned short f2bf(float x) {
    unsigned int u = __float_as_uint(x);
    unsigned int r = (u + 0x7FFFu + ((u >> 16) & 1u)) >> 16;
    return (unsigned short)r;
}

// -------- Kernel 1: pipelined v-chunked LDS staging -----------------------
// Block = (b, 64 l's). Chunk c = preds[b, :, 4c:4c+4, l0:l0+64] = 64 rows
// x 256 B = 16 KB, double-buffered (2x16 KB LDS -> 4 blocks/CU).
// Pipeline: stage(0); for c: barrier(drains DMA(c)) -> issue DMA(c+1) ->
// compute(c).  DMA(c+1) overlaps compute(c); every block keeps one DMA
// outstanding -> HBM saturated.  All scalar loads in prologue.
// NOTE: __launch_bounds__ min_waves MUST stay 2 — at 4 the allocator
// spills acc[] to scratch (R8: +100 MB WRITE, 110 us).

static __device__ __forceinline__ void k1_stage(
    const float* __restrict__ preds, float* __restrict__ dst,
    int b, int v0, int l0, int L, int lane, int wave)
{
    // 64 LDS rows r = i*4+vc; wave stages 16 rows = 4 instrs x 4 rows (1 KB)
#pragma unroll
    for (int n = 0; n < 4; ++n) {
        int r0 = wave * 16 + n * 4;               // wave-uniform LDS row group
        int r = r0 + (lane >> 4);                 // this lane's row
        int grow = b * 256 + (r >> 2) * 16 + v0 + (r & 3);
        const float* g = preds + (size_t)grow * L + l0 + (lane & 15) * 4;
        __builtin_amdgcn_global_load_lds(
            (const __attribute__((address_space(1))) unsigned int*)g,
            (__attribute__((address_space(3))) unsigned int*)(dst + r0 * 64),
            16, 0, 0);
    }
}

template<int W>
static __device__ __forceinline__ void k1_chunk(
    const float* __restrict__ xsb,                // 64 rows x 64 f32, r=i*4+vc
    const float* __restrict__ ty,                 // 16 scaled targets (W==0)
    const float* __restrict__ sw,                 // 16 scale*weight values
    int v0, int lane, float* __restrict__ acc)
{
    const int base = (W == 0) ? 0 : 34 * W - 16;  // first pair idx
    const int npair = (W == 0) ? 18 : 34;
    const int aoff = (W == 0) ? 16 : 0;

#pragma unroll
    for (int vc = 0; vc < 4; ++vc) {
        const int v = v0 + vc;                    // compile-time after unroll
        float s = sw[v];
        float x[M];
#pragma unroll
        for (int i = 0; i < M; ++i)
            x[i] = xsb[(i * 4 + vc) * 64 + lane] * s;
        if (W == 0) {
            float y = ty[v];
#pragma unroll
            for (int i = 0; i < M; ++i) {
                float d = x[i] - y;
                acc[i] = fmaf(d, d, acc[i]);
            }
        }
        int k = 0;
#pragma unroll
        for (int i = 0; i < M; ++i) {
#pragma unroll
            for (int j = i + 1; j < M; ++j) {
                if (k >= base && k < base + npair) {
                    float d = x[i] - x[j];
                    acc[aoff + k - base] = fmaf(d, d, acc[aoff + k - base]);
                }
                ++k;
            }
        }
    }
}

__global__ __launch_bounds__(256, 2)
void k1_pairsums(const float* __restrict__ preds, const float* __restrict__ target,
                 const float* __restrict__ weights, const float* __restrict__ scale,
                 const float* __restrict__ masks,
                 unsigned short* __restrict__ S, unsigned short* __restrict__ maskbf,
                 int L)
{
    __shared__ float xs[2][4096];                 // 2 x 16 KB
    int t = (int)threadIdx.x;
    int lane = t & 63, wave = t >> 6;
    int l0 = (int)blockIdx.x * 64;
    int b = (int)blockIdx.y;

    k1_stage(preds, &xs[0][0], b, 0, l0, L, lane, wave);

    // prologue: ALL scalar global loads (no vmcnt waits inside the K-loop)
    float wl = weights[l0 + lane];
    float sw[V];
#pragma unroll
    for (int v = 0; v < V; ++v) sw[v] = scale[v] * wl;
    float ty[V];
    if (wave == 0) {
#pragma unroll
        for (int v = 0; v < V; ++v)
            ty[v] = target[(size_t)(b * V + v) * L + l0 + lane] * sw[v];
    }
    if (b == 0) {
#pragma unroll
        for (int pp = 0; pp < 8; ++pp) {
            int p = wave * 8 + pp;
            maskbf[(size_t)p * L + l0 + lane] =
                (masks[(size_t)p * L + l0 + lane] != 0.0f) ? (unsigned short)0x3F80
                                                           : (unsigned short)0;
        }
    }

    float acc[34];
#pragma unroll
    for (int r = 0; r < 34; ++r) acc[r] = 0.0f;

#pragma unroll
    for (int c = 0; c < 4; ++c) {
        __syncthreads();                          // DMA(c) complete; buffer safe
        if (c < 3)                                // DMA(c+1) flies during compute(c)
            k1_stage(preds, &xs[(c + 1) & 1][0], b, (c + 1) * 4, l0, L, lane, wave);
        const float* xsb = &xs[c & 1][0];
        switch (wave) {
            case 0: k1_chunk<0>(xsb, ty, sw, c * 4, lane, acc); break;
            case 1: k1_chunk<1>(xsb, ty, sw, c * 4, lane, acc); break;
            case 2: k1_chunk<2>(xsb, ty, sw, c * 4, lane, acc); break;
            default: k1_chunk<3>(xsb, ty, sw, c * 4, lane, acc); break;
        }
    }

#pragma unroll
    for (int r = 0; r < 34; ++r)
        S[(size_t)(b * NROWB + 34 * wave + r) * L + l0 + lane] = f2bf(acc[r]);
}

// -------- Kernel 2: MFMA GEMM  D2[row][p] = sum_l S[row][l] * maskbf[p][l]
__global__ __launch_bounds__(256, 4)
void k2_mfma(const unsigned short* __restrict__ S,
             const unsigned short* __restrict__ maskbf,
             float* __restrict__ D2p, float* __restrict__ out, int L)
{
    if (blockIdx.x == 0 && blockIdx.y == 0 && threadIdx.x == 0)
        out[0] = 0.0f;                            // k3 atomics stream-ordered after k2

    int lane = (int)(threadIdx.x & 63);
    int wave = (int)(threadIdx.x >> 6);
    int mtile = blockIdx.x;            // 0..16
    int z = blockIdx.y;                // 0..KZ-1
    int zw = z * 4 + wave;             // 0..127 K-workers

    const int q = KSTEPS / NWORK;      // 9
    const int rem = KSTEPS % NWORK;    // 108
    int start = zw * q + (zw < rem ? zw : rem);
    int cnt = q + (zw < rem ? 1 : 0);

    const unsigned short* Arow =
        S + (size_t)(mtile * 16 + (lane & 15)) * L + (lane >> 4) * 8;
    const unsigned short* B0 =
        maskbf + (size_t)(lane & 15) * L + (lane >> 4) * 8;
    const unsigned short* B1 =
        maskbf + (size_t)(16 + (lane & 15)) * L + (lane >> 4) * 8;

    f32x4 acc0 = {0.f, 0.f, 0.f, 0.f};
    f32x4 acc1 = {0.f, 0.f, 0.f, 0.f};

    for (int s = 0; s < cnt; ++s) {
        int k0 = (start + s) * 32;
        bf16x8 a  = *(const bf16x8*)(Arow + k0);
        bf16x8 b0 = *(const bf16x8*)(B0 + k0);
        bf16x8 b1 = *(const bf16x8*)(B1 + k0);
        acc0 = __builtin_amdgcn_mfma_f32_16x16x32_bf16(a, b0, acc0, 0, 0, 0);
        acc1 = __builtin_amdgcn_mfma_f32_16x16x32_bf16(a, b1, acc1, 0, 0, 0);
    }

    __shared__ float red[4][512];
    int c16 = lane & 15;
#pragma unroll
    for (int reg = 0; reg < 4; ++reg) {
        int r16 = (lane >> 4) * 4 + reg;
        red[wave][r16 * 16 + c16]       = acc0[reg];
        red[wave][256 + r16 * 16 + c16] = acc1[reg];
    }
    __syncthreads();
    int t = (int)threadIdx.x;
#pragma unroll
    for (int u = t; u < 512; u += 256) {
        float v = red[0][u] + red[1][u] + red[2][u] + red[3][u];
        D2p[((size_t)z * 17 + mtile) * 512 + u] = v;
    }
}

// -------- Kernel 3: parallel z-sum, sqrt, weighted reduce, atomic ---------
__global__ __launch_bounds__(256, 2)
void k3_finalize(const float* __restrict__ D2p, const int* __restrict__ beta_p,
                 float* __restrict__ out)
{
    int t = (int)threadIdx.x;
    int e = blockIdx.x * 256 + t;          // 0..8703, grid exact
    int mtile = e >> 9;
    int flat = e & 511;

    float vbuf[KZ];
#pragma unroll
    for (int z = 0; z < KZ; ++z)
        vbuf[z] = D2p[((size_t)z * 17 + mtile) * 512 + flat];

    float a0 = 0.f, a1 = 0.f, a2 = 0.f, a3 = 0.f;
#pragma unroll
    for (int z = 0; z < KZ; z += 4) {
        a0 += vbuf[z + 0]; a1 += vbuf[z + 1];
        a2 += vbuf[z + 2]; a3 += vbuf[z + 3];
    }
    float d2 = fmaxf((a0 + a1) + (a2 + a3), 0.0f);
    float beta = (float)beta_p[0];
    float d = (beta == 1.0f) ? sqrtf(d2) : powf(d2, 0.5f * beta);

    const float wa = 1.0f / (float)(BS * M);
    const float wb = -1.0f / (float)(BS * M * (M - 1));
    int row = mtile * 16 + ((flat >> 4) & 15);
    int local = row % NROWB;
    float sum = ((local < M) ? wa : wb) * d;

    int lane = t & 63, wv = t >> 6;
#pragma unroll
    for (int off = 32; off > 0; off >>= 1)
        sum += __shfl_down(sum, off, 64);
    __shared__ float red[4];
    if (lane == 0) red[wv] = sum;
    __syncthreads();
    if (t == 0)
        atomicAdd(out, red[0] + red[1] + red[2] + red[3]);
}

extern "C" void kernel_launch(void* const* d_in, const int* in_sizes, int n_in,
                              void* d_out, int out_size, void* d_ws, size_t ws_size,
                              hipStream_t stream)
{
    const float* preds   = (const float*)d_in[0];
    const float* target  = (const float*)d_in[1];
    const float* weights = (const float*)d_in[2];
    const float* scale   = (const float*)d_in[3];
    const float* masks   = (const float*)d_in[4];
    const int*   beta    = (const int*)d_in[5];
    float* out = (float*)d_out;

    int L = in_sizes[2];   // 40320 = 630*64 = 1260*32

    unsigned short* S = (unsigned short*)d_ws;                   // 272*L bf16
    size_t s_bytes = (size_t)NROWS * (size_t)L * sizeof(unsigned short);
    unsigned short* maskbf = (unsigned short*)((char*)d_ws + ((s_bytes + 255) & ~(size_t)255));
    size_t m_bytes = (size_t)PMASK * (size_t)L * sizeof(unsigned short);
    float* D2p = (float*)((char*)maskbf + ((m_bytes + 255) & ~(size_t)255)); // KZ*17*512 f32

    dim3 g1(L / 64, BS);                   // 630 x 2
    k1_pairsums<<<g1, 256, 0, stream>>>(preds, target, weights, scale, masks,
                                        S, maskbf, L);

    dim3 g2(17, KZ);
    k2_mfma<<<g2, 256, 0, stream>>>(S, maskbf, D2p, out, L);

    k3_finalize<<<(NROWS * PMASK) / 256, 256, 0, stream>>>(D2p, beta, out);
}